// Round 4
// baseline (3886.584 us; speedup 1.0000x reference)
//
#include <hip/hip_runtime.h>
#include <hip/hip_bf16.h>
#include <hip/hip_cooperative_groups.h>
#include <cstddef>

namespace cg = cooperative_groups;

#define B 64
#define S 128
#define H 1024
#define V 32000
#define T 10
#define H3 3072
#define NB 512
#define NTHR 256
#define NCHUNK 500   // V/64

typedef __bf16 bf16x8 __attribute__((ext_vector_type(8)));
typedef float f32x4 __attribute__((ext_vector_type(4)));
typedef unsigned short ushort8v __attribute__((ext_vector_type(8)));

__device__ inline unsigned short f2b(float f) {
    __hip_bfloat16 h = __float2bfloat16(f);
    return *reinterpret_cast<unsigned short*>(&h);
}
__device__ inline float b2f(unsigned short u) {
    return __uint_as_float(((unsigned)u) << 16);
}

// ---------------- one-time conversion / build kernels ----------------

__global__ void conv_f2b(const float* __restrict__ src, unsigned short* __restrict__ dst, int n4) {
    int i = blockIdx.x * 256 + threadIdx.x;
    if (i >= n4) return;
    float4 v = reinterpret_cast<const float4*>(src)[i];
    ushort4 o = { f2b(v.x), f2b(v.y), f2b(v.z), f2b(v.w) };
    reinterpret_cast<ushort4*>(dst)[i] = o;
}

__global__ void build_wcat(const float* __restrict__ gwh, const float* __restrict__ Wa_w,
                           unsigned short* __restrict__ dst) {
    int i = blockIdx.x * 256 + threadIdx.x;
    int e = i * 4;
    int n = e >> 10, k = e & 1023;
    const float* src = (n < H3) ? (gwh + (size_t)n * H + k) : (Wa_w + (size_t)(n - H3) * H + k);
    float4 v = *reinterpret_cast<const float4*>(src);
    ushort4 o = { f2b(v.x), f2b(v.y), f2b(v.z), f2b(v.w) };
    reinterpret_cast<ushort4*>(dst)[i] = o;
}

__global__ void build_catbias(const float* __restrict__ gbh, const float* __restrict__ Wa_b,
                              float* __restrict__ dst) {
    int n = blockIdx.x * 256 + threadIdx.x;
    dst[n] = (n < H3) ? gbh[n] : Wa_b[n - H3];
}

__global__ void build_wslice(const float* __restrict__ gwi, unsigned short* __restrict__ dst, int off) {
    int i = blockIdx.x * 256 + threadIdx.x;
    int e = i * 4;
    int n = e >> 10, k = e & 1023;
    float4 v = *reinterpret_cast<const float4*>(gwi + (size_t)n * 2 * H + off + k);
    ushort4 o = { f2b(v.x), f2b(v.y), f2b(v.z), f2b(v.w) };
    reinterpret_cast<ushort4*>(dst)[i] = o;
}

__global__ void embgath_kernel(const float* __restrict__ emb, const int* __restrict__ tgt,
                               unsigned short* __restrict__ dst) {
    int b = blockIdx.y, t = blockIdx.z;
    int j = blockIdx.x * 256 + threadIdx.x;
    int tok = (t == 0) ? 0 : tgt[b * T + (t - 1)];
    dst[((size_t)t * B + b) * H + j] = f2b(emb[(size_t)tok * H + j]);
}

// ---------------- the persistent cooperative mega-kernel ----------------

struct MegaP {
    const unsigned short *enc_bf, *Ua_bf, *embg, *Wcat, *Wctx, *Wemb;
    const float *Ua_b, *gbi, *catbias, *Va_w, *Va_b, *out_w, *out_b;
    unsigned short *ua_bf, *hbf, *ctx_bf, *outs_bf;
    float *ghq, *gi_emb, *gi_ctx, *hbuf, *scores, *log_probs, *h_final, *attns, *lse;
    float2 *stats;
};

struct SmemT {
    unsigned short As[64][72];
    unsigned short Bs[64][72];
    float red[64][4];
    float red2[64][4];
    float sc[128];
    float tmp[128];
    float fm[256];
    float fs[256];
};

// C tile [m0:m0+64, n0:n0+64] = A[M,K](bf16) @ Bw[N,K]^T + bias
template <int B_F32, int OUT_BF16, int STATS>
__device__ __forceinline__ void gemm_tile(const unsigned short* __restrict__ A,
                                          const void* __restrict__ Bw,
                                          const float* __restrict__ bias,
                                          void* __restrict__ Cout, float2* __restrict__ stats,
                                          int m0, int n0, int ldC, int K, SmemT& sm) {
    const int tid = threadIdx.x;
    const int lane = tid & 63, wvb = tid >> 6, quad = lane >> 4, fr = lane & 15;
    const int srow = tid >> 2, sc16 = (tid & 3) * 16;
    f32x4 acc[4] = {};
    for (int k0 = 0; k0 < K; k0 += 64) {
        const unsigned short* ap = A + (size_t)(m0 + srow) * K + k0 + sc16;
        *reinterpret_cast<bf16x8*>(&sm.As[srow][sc16])     = *reinterpret_cast<const bf16x8*>(ap);
        *reinterpret_cast<bf16x8*>(&sm.As[srow][sc16 + 8]) = *reinterpret_cast<const bf16x8*>(ap + 8);
        if (B_F32) {
            const float* bp = (const float*)Bw + (size_t)(n0 + srow) * K + k0 + sc16;
            float4 f0 = *reinterpret_cast<const float4*>(bp);
            float4 f1 = *reinterpret_cast<const float4*>(bp + 4);
            float4 f2 = *reinterpret_cast<const float4*>(bp + 8);
            float4 f3 = *reinterpret_cast<const float4*>(bp + 12);
            ushort8v u0, u1;
            u0[0]=f2b(f0.x); u0[1]=f2b(f0.y); u0[2]=f2b(f0.z); u0[3]=f2b(f0.w);
            u0[4]=f2b(f1.x); u0[5]=f2b(f1.y); u0[6]=f2b(f1.z); u0[7]=f2b(f1.w);
            u1[0]=f2b(f2.x); u1[1]=f2b(f2.y); u1[2]=f2b(f2.z); u1[3]=f2b(f2.w);
            u1[4]=f2b(f3.x); u1[5]=f2b(f3.y); u1[6]=f2b(f3.z); u1[7]=f2b(f3.w);
            *reinterpret_cast<ushort8v*>(&sm.Bs[srow][sc16])     = u0;
            *reinterpret_cast<ushort8v*>(&sm.Bs[srow][sc16 + 8]) = u1;
        } else {
            const unsigned short* bp = (const unsigned short*)Bw + (size_t)(n0 + srow) * K + k0 + sc16;
            *reinterpret_cast<bf16x8*>(&sm.Bs[srow][sc16])     = *reinterpret_cast<const bf16x8*>(bp);
            *reinterpret_cast<bf16x8*>(&sm.Bs[srow][sc16 + 8]) = *reinterpret_cast<const bf16x8*>(bp + 8);
        }
        __syncthreads();
        #pragma unroll
        for (int ks = 0; ks < 2; ++ks) {
            const int kg = quad * 8 + 32 * ks;
            bf16x8 bb = *reinterpret_cast<const bf16x8*>(&sm.Bs[16 * wvb + fr][kg]);
            #pragma unroll
            for (int m = 0; m < 4; ++m) {
                bf16x8 a = *reinterpret_cast<const bf16x8*>(&sm.As[16 * m + fr][kg]);
                acc[m] = __builtin_amdgcn_mfma_f32_16x16x32_bf16(a, bb, acc[m], 0, 0, 0);
            }
        }
        __syncthreads();
    }
    const int col = n0 + 16 * wvb + fr;
    const float bv = bias ? bias[col] : 0.f;
    #pragma unroll
    for (int m = 0; m < 4; ++m)
        #pragma unroll
        for (int i = 0; i < 4; ++i) {
            int row = m0 + 16 * m + quad * 4 + i;
            float v = acc[m][i] + bv;
            if (OUT_BF16)
                ((unsigned short*)Cout)[(size_t)row * ldC + col] = f2b(v);
            else
                ((float*)Cout)[(size_t)row * ldC + col] = v;
            if (STATS) acc[m][i] = v;
        }
    if (STATS) {
        #pragma unroll
        for (int m = 0; m < 4; ++m)
            #pragma unroll
            for (int i = 0; i < 4; ++i) {
                float x = acc[m][i];
                x = fmaxf(x, __shfl_xor(x, 1)); x = fmaxf(x, __shfl_xor(x, 2));
                x = fmaxf(x, __shfl_xor(x, 4)); x = fmaxf(x, __shfl_xor(x, 8));
                if (fr == 0) sm.red[16 * m + quad * 4 + i][wvb] = x;
            }
        __syncthreads();
        #pragma unroll
        for (int m = 0; m < 4; ++m)
            #pragma unroll
            for (int i = 0; i < 4; ++i) {
                int rl = 16 * m + quad * 4 + i;
                float Mr = fmaxf(fmaxf(sm.red[rl][0], sm.red[rl][1]),
                                 fmaxf(sm.red[rl][2], sm.red[rl][3]));
                float e = expf(acc[m][i] - Mr);
                e += __shfl_xor(e, 1); e += __shfl_xor(e, 2);
                e += __shfl_xor(e, 4); e += __shfl_xor(e, 8);
                if (fr == 0) sm.red2[rl][wvb] = e;
            }
        __syncthreads();
        if (tid < 64) {
            float Mr = fmaxf(fmaxf(sm.red[tid][0], sm.red[tid][1]),
                             fmaxf(sm.red[tid][2], sm.red[tid][3]));
            float Sv = sm.red2[tid][0] + sm.red2[tid][1] + sm.red2[tid][2] + sm.red2[tid][3];
            stats[(size_t)(m0 + tid) * NCHUNK + (n0 >> 6)] = make_float2(Mr, Sv);
        }
        __syncthreads();
    }
}

__global__ __launch_bounds__(NTHR, 2) void mega(MegaP p) {
    cg::grid_group grid = cg::this_grid();
    const int bid = blockIdx.x, tid = threadIdx.x;
    __shared__ SmemT sm;

    // ---- phase 0: ua_keys (2048 tiles) + gi_emb (480 tiles), block-contiguous, m-fastest
    {
        const int total = 2048 + 480;
        int lo = (int)(((long)bid * total) / NB), hi = (int)(((long)(bid + 1) * total) / NB);
        for (int w = lo; w < hi; ++w) {
            if (w < 2048) {
                int m = w & 127, n = w >> 7;
                gemm_tile<0, 1, 0>(p.enc_bf, p.Ua_bf, p.Ua_b, p.ua_bf, nullptr,
                                   m * 64, n * 64, H, H, sm);
            } else {
                int w2 = w - 2048;
                int m = w2 % 10, n = w2 / 10;
                gemm_tile<0, 0, 0>(p.embg, p.Wemb, p.gbi, p.gi_emb, nullptr,
                                   m * 64, n * 64, H3, H, sm);
            }
        }
    }
    grid.sync();

    for (int t = 0; t < T; ++t) {
        // ---- P1: ghq[64,4096] = hbf @ Wcat^T + catbias
        for (int w = bid; w < 64; w += NB)
            gemm_tile<0, 0, 0>(p.hbf, p.Wcat, p.catbias, p.ghq, nullptr, 0, w * 64, 4096, H, sm);
        grid.sync();

        // ---- P2a: scores[b,s] = sum_h tanh(q+key)*va + va_b
        for (int w = bid; w < B * 4; w += NB) {
            int b = w >> 2, sg = w & 3;
            int wvb = tid >> 6, lane = tid & 63;
            int s = sg * 32 + wvb * 8 + (lane >> 3);
            int c = lane & 7;                       // h-chunk of 128
            const float* qp = p.ghq + (size_t)b * 4096 + H3 + c * 128;
            const float* vp = p.Va_w + c * 128;
            const unsigned short* kp = p.ua_bf + ((size_t)b * S + s) * H + c * 128;
            float acc = 0.f;
            for (int j = 0; j < 16; ++j) {
                float qv[8], vv[8];
                *reinterpret_cast<float4*>(&qv[0]) = *reinterpret_cast<const float4*>(qp + j * 8);
                *reinterpret_cast<float4*>(&qv[4]) = *reinterpret_cast<const float4*>(qp + j * 8 + 4);
                *reinterpret_cast<float4*>(&vv[0]) = *reinterpret_cast<const float4*>(vp + j * 8);
                *reinterpret_cast<float4*>(&vv[4]) = *reinterpret_cast<const float4*>(vp + j * 8 + 4);
                ushort8v k8 = *reinterpret_cast<const ushort8v*>(kp + j * 8);
                #pragma unroll
                for (int e = 0; e < 8; ++e) acc += tanhf(qv[e] + b2f(k8[e])) * vv[e];
            }
            acc += __shfl_xor(acc, 1); acc += __shfl_xor(acc, 2); acc += __shfl_xor(acc, 4);
            if ((lane & 7) == 0) p.scores[b * S + s] = acc + p.Va_b[0];
        }
        grid.sync();

        // ---- P2b: softmax + ctx (+ attns write)
        for (int w = bid; w < B * 4; w += NB) {
            int b = w >> 2, hg = w & 3;
            if (tid < 128) { sm.sc[tid] = p.scores[b * S + tid]; }
            __syncthreads();
            if (tid < 128) sm.tmp[tid] = sm.sc[tid];
            __syncthreads();
            for (int off = 64; off > 0; off >>= 1) {
                if (tid < off) sm.tmp[tid] = fmaxf(sm.tmp[tid], sm.tmp[tid + off]);
                __syncthreads();
            }
            float mx = sm.tmp[0];
            __syncthreads();
            if (tid < 128) { sm.sc[tid] = expf(sm.sc[tid] - mx); sm.tmp[tid] = sm.sc[tid]; }
            __syncthreads();
            for (int off = 64; off > 0; off >>= 1) {
                if (tid < off) sm.tmp[tid] += sm.tmp[tid + off];
                __syncthreads();
            }
            float inv = 1.f / sm.tmp[0];
            __syncthreads();
            int h = hg * 256 + tid;
            const unsigned short* eb = p.enc_bf + (size_t)b * S * H + h;
            float acc = 0.f;
            #pragma unroll 8
            for (int s2 = 0; s2 < S; ++s2) acc += sm.sc[s2] * b2f(eb[(size_t)s2 * H]);
            p.ctx_bf[(size_t)b * H + h] = f2b(acc * inv);
            if (hg == 0 && tid < 128)
                p.attns[((size_t)b * T + t) * S + tid] = sm.sc[tid] * inv;
            __syncthreads();
        }
        grid.sync();

        // ---- P3: gi_ctx[64,3072] = ctx_bf @ Wctx^T
        for (int w = bid; w < 48; w += NB)
            gemm_tile<0, 0, 0>(p.ctx_bf, p.Wctx, nullptr, p.gi_ctx, nullptr, 0, w * 64, H3, H, sm);
        grid.sync();

        // ---- P4: GRU gates
        for (int w = bid; w < B * 4; w += NB) {
            int b = w >> 2, jg = w & 3;
            int j = jg * 256 + tid;
            const float* ge = p.gi_emb + ((size_t)t * B + b) * H3;
            const float* gc = p.gi_ctx + (size_t)b * H3;
            const float* gh = p.ghq + (size_t)b * 4096;
            float r = 1.f / (1.f + expf(-(ge[j] + gc[j] + gh[j])));
            float z = 1.f / (1.f + expf(-(ge[H + j] + gc[H + j] + gh[H + j])));
            float n = tanhf(ge[2 * H + j] + gc[2 * H + j] + r * gh[2 * H + j]);
            float hv = p.hbuf[(size_t)b * H + j];
            float hn = (1.f - z) * n + z * hv;
            p.hbuf[(size_t)b * H + j] = hn;
            p.hbf[(size_t)b * H + j] = f2b(hn);
            p.outs_bf[((size_t)b * T + t) * H + j] = f2b(hn);
            if (t == T - 1) p.h_final[(size_t)b * H + j] = hn;
        }
        grid.sync();
    }

    // ---- logits: [640, 32000] = outs_bf @ out_w^T + out_b, fused softmax stats
    {
        const int total = 10 * NCHUNK;   // m-tiles 10, n-tiles 500; m fastest
        int lo = (int)(((long)bid * total) / NB), hi = (int)(((long)(bid + 1) * total) / NB);
        for (int w = lo; w < hi; ++w) {
            int m = w % 10, n = w / 10;
            gemm_tile<1, 0, 1>(p.outs_bf, p.out_w, p.out_b, p.log_probs, p.stats,
                               m * 64, n * 64, V, H, sm);
        }
    }
    grid.sync();

    // ---- LSE per row
    for (int row = bid; row < B * T; row += NB) {
        float mv = -1e30f, sv = 0.f;
        for (int c = tid; c < NCHUNK; c += NTHR) {
            float2 st = p.stats[(size_t)row * NCHUNK + c];
            float nm = fmaxf(mv, st.x);
            sv = sv * expf(mv - nm) + st.y * expf(st.x - nm);
            mv = nm;
        }
        sm.fm[tid] = mv; sm.fs[tid] = sv;
        __syncthreads();
        for (int off = 128; off > 0; off >>= 1) {
            if (tid < off) {
                float m2 = sm.fm[tid + off], s2 = sm.fs[tid + off];
                float nm = fmaxf(sm.fm[tid], m2);
                sm.fs[tid] = sm.fs[tid] * expf(sm.fm[tid] - nm) + s2 * expf(m2 - nm);
                sm.fm[tid] = nm;
            }
            __syncthreads();
        }
        if (tid == 0) p.lse[row] = sm.fm[0] + logf(sm.fs[0]);
        __syncthreads();
    }
    grid.sync();

    // ---- subtract LSE
    {
        const int n4 = B * T * (V / 4);
        float4* lp = reinterpret_cast<float4*>(p.log_probs);
        for (int i = bid * NTHR + tid; i < n4; i += NB * NTHR) {
            int row = i / (V / 4);
            float l = p.lse[row];
            float4 v = lp[i];
            v.x -= l; v.y -= l; v.z -= l; v.w -= l;
            lp[i] = v;
        }
    }
}

// ---------------- host ----------------

extern "C" void kernel_launch(void* const* d_in, const int* in_sizes, int n_in,
                              void* d_out, int out_size, void* d_ws, size_t ws_size,
                              hipStream_t stream) {
    const float* enc   = (const float*)d_in[0];
    const float* h0    = (const float*)d_in[1];
    const int*   tgt   = (const int*)d_in[2];
    const float* emb   = (const float*)d_in[3];
    const float* Wa_w  = (const float*)d_in[4];
    const float* Wa_b  = (const float*)d_in[5];
    const float* Ua_w  = (const float*)d_in[6];
    const float* Ua_b  = (const float*)d_in[7];
    const float* Va_w  = (const float*)d_in[8];
    const float* Va_b  = (const float*)d_in[9];
    const float* gwi   = (const float*)d_in[10];
    const float* gwh   = (const float*)d_in[11];
    const float* gbi   = (const float*)d_in[12];
    const float* gbh   = (const float*)d_in[13];
    const float* out_w = (const float*)d_in[14];
    const float* out_b = (const float*)d_in[15];

    float* out       = (float*)d_out;
    float* log_probs = out;                          // [B*T, V]
    float* h_final   = out + (size_t)B * T * V;      // [B, H]
    float* attns     = h_final + (size_t)B * H;      // [B, T, S]

    char* pp = (char*)d_ws;
    auto alloc = [&](size_t bytes) { char* r = pp; pp += (bytes + 255) & ~(size_t)255; return r; };
    unsigned short* ua_bf   = (unsigned short*)alloc((size_t)B * S * H * 2);
    unsigned short* enc_bf  = (unsigned short*)alloc((size_t)B * S * H * 2);
    unsigned short* Ua_bf   = (unsigned short*)alloc((size_t)H * H * 2);
    unsigned short* Wcat    = (unsigned short*)alloc((size_t)4096 * H * 2);
    unsigned short* Wctx    = (unsigned short*)alloc((size_t)H3 * H * 2);
    unsigned short* Wemb    = (unsigned short*)alloc((size_t)H3 * H * 2);
    float*          catbias = (float*)alloc(4096 * 4);
    unsigned short* embg    = (unsigned short*)alloc((size_t)T * B * H * 2);
    float*          gi_emb  = (float*)alloc((size_t)T * B * H3 * 4);
    float*          hbuf    = (float*)alloc((size_t)B * H * 4);
    unsigned short* hbf     = (unsigned short*)alloc((size_t)B * H * 2);
    float*          ghq     = (float*)alloc((size_t)B * 4096 * 4);
    unsigned short* ctx_bf  = (unsigned short*)alloc((size_t)B * H * 2);
    float*          gi_ctx  = (float*)alloc((size_t)B * H3 * 4);
    unsigned short* outs_bf = (unsigned short*)alloc((size_t)B * T * H * 2);
    float*          scores  = (float*)alloc((size_t)B * S * 4);
    float2*         stats   = (float2*)alloc((size_t)B * T * NCHUNK * 8);
    float*          lse     = (float*)alloc((size_t)B * T * 4);

    // one-time builds
    conv_f2b<<<B * S * H / 4 / 256, 256, 0, stream>>>(enc, enc_bf, B * S * H / 4);
    conv_f2b<<<H * H / 4 / 256, 256, 0, stream>>>(Ua_w, Ua_bf, H * H / 4);
    conv_f2b<<<B * H / 4 / 256, 256, 0, stream>>>(h0, hbf, B * H / 4);
    build_wcat<<<4096 * H / 4 / 256, 256, 0, stream>>>(gwh, Wa_w, Wcat);
    build_catbias<<<4096 / 256, 256, 0, stream>>>(gbh, Wa_b, catbias);
    build_wslice<<<H3 * H / 4 / 256, 256, 0, stream>>>(gwi, Wemb, 0);
    build_wslice<<<H3 * H / 4 / 256, 256, 0, stream>>>(gwi, Wctx, H);
    embgath_kernel<<<dim3(H / 256, B, T), 256, 0, stream>>>(emb, tgt, embg);
    hipMemcpyAsync(hbuf, h0, (size_t)B * H * sizeof(float), hipMemcpyDeviceToDevice, stream);

    MegaP prm;
    prm.enc_bf = enc_bf; prm.Ua_bf = Ua_bf; prm.embg = embg;
    prm.Wcat = Wcat; prm.Wctx = Wctx; prm.Wemb = Wemb;
    prm.Ua_b = Ua_b; prm.gbi = gbi; prm.catbias = catbias;
    prm.Va_w = Va_w; prm.Va_b = Va_b; prm.out_w = out_w; prm.out_b = out_b;
    prm.ua_bf = ua_bf; prm.hbf = hbf; prm.ctx_bf = ctx_bf; prm.outs_bf = outs_bf;
    prm.ghq = ghq; prm.gi_emb = gi_emb; prm.gi_ctx = gi_ctx; prm.hbuf = hbuf;
    prm.scores = scores; prm.log_probs = log_probs; prm.h_final = h_final;
    prm.attns = attns; prm.lse = lse; prm.stats = stats;

    void* kargs[] = { (void*)&prm };
    hipLaunchCooperativeKernel((void*)mega, dim3(NB), dim3(NTHR), kargs, 0, stream);
}

// Round 5
// 1001.416 us; speedup vs baseline: 3.8811x; 3.8811x over previous
//
#include <hip/hip_runtime.h>
#include <hip/hip_bf16.h>
#include <cstddef>

#define B 64
#define S 128
#define H 1024
#define V 32000
#define T 10
#define H3 3072
#define NCHUNK 250

typedef __bf16 bf16x8 __attribute__((ext_vector_type(8)));
typedef float f32x4 __attribute__((ext_vector_type(4)));
typedef unsigned short ushort8v __attribute__((ext_vector_type(8)));

__device__ inline unsigned short f2b(float f) {
    __hip_bfloat16 h = __float2bfloat16(f);
    return *reinterpret_cast<unsigned short*>(&h);
}
__device__ inline float b2f(unsigned short u) {
    return __uint_as_float(((unsigned)u) << 16);
}
__device__ inline float fast_tanh(float x) {
    // 1 - 2/(e^{2x}+1); exact limits at +-inf
    float e = __expf(2.f * x);
    return 1.f - 2.f * __builtin_amdgcn_rcpf(e + 1.f);
}
__device__ inline float fast_sigmoid(float x) {
    return __builtin_amdgcn_rcpf(1.f + __expf(-x));
}

// ---------------- one-time conversion / build kernels ----------------

__global__ void conv_f2b(const float* __restrict__ src, unsigned short* __restrict__ dst, int n4) {
    int i = blockIdx.x * 256 + threadIdx.x;
    if (i >= n4) return;
    float4 v = reinterpret_cast<const float4*>(src)[i];
    ushort4 o = { f2b(v.x), f2b(v.y), f2b(v.z), f2b(v.w) };
    reinterpret_cast<ushort4*>(dst)[i] = o;
}

// Wcat[4096,1024] = rows 0..3071: gru_wh ; rows 3072..4095: Wa_w (bf16)
__global__ void build_wcat(const float* __restrict__ gwh, const float* __restrict__ Wa_w,
                           unsigned short* __restrict__ dst) {
    int i = blockIdx.x * 256 + threadIdx.x;
    int e = i * 4;
    int n = e >> 10, k = e & 1023;
    const float* src = (n < H3) ? (gwh + (size_t)n * H + k) : (Wa_w + (size_t)(n - H3) * H + k);
    float4 v = *reinterpret_cast<const float4*>(src);
    ushort4 o = { f2b(v.x), f2b(v.y), f2b(v.z), f2b(v.w) };
    reinterpret_cast<ushort4*>(dst)[i] = o;
}

__global__ void build_catbias(const float* __restrict__ gbh, const float* __restrict__ Wa_b,
                              float* __restrict__ dst) {
    int n = blockIdx.x * 256 + threadIdx.x;
    dst[n] = (n < H3) ? gbh[n] : Wa_b[n - H3];
}

// slice gru_wi[:, off:off+H] -> [3072,1024] bf16
__global__ void build_wslice(const float* __restrict__ gwi, unsigned short* __restrict__ dst, int off) {
    int i = blockIdx.x * 256 + threadIdx.x;
    int e = i * 4;
    int n = e >> 10, k = e & 1023;
    float4 v = *reinterpret_cast<const float4*>(gwi + (size_t)n * 2 * H + off + k);
    ushort4 o = { f2b(v.x), f2b(v.y), f2b(v.z), f2b(v.w) };
    reinterpret_cast<ushort4*>(dst)[i] = o;
}

__global__ void embgath_kernel(const float* __restrict__ emb, const int* __restrict__ tgt,
                               unsigned short* __restrict__ dst) {
    int b = blockIdx.y, t = blockIdx.z;
    int j = blockIdx.x * 256 + threadIdx.x;
    int tok = (t == 0) ? 0 : tgt[b * T + (t - 1)];
    dst[((size_t)t * B + b) * H + j] = f2b(emb[(size_t)tok * H + j]);
}

// ---------------- big MFMA GEMM: 128x128 tile, BK=64, 512 thr ----------------
// C[M,N] = A[M,K](bf16) @ Bw[N,K]^T(bf16) + bias ; grid (M/128, N/128), x fastest
template <int OUT_BF16, int STATS>
__global__ __launch_bounds__(512) void gemm_big(const unsigned short* __restrict__ A,
                                                const unsigned short* __restrict__ Bw,
                                                const float* __restrict__ bias,
                                                void* __restrict__ Cout,
                                                float2* __restrict__ stats,
                                                int M, int N, int K) {
    __shared__ unsigned short As[128][72];
    __shared__ unsigned short Bs[128][72];
    __shared__ float mred[128][4];
    __shared__ float sred[128][4];
    const int bm = blockIdx.x * 128, bn = blockIdx.y * 128;
    const int tid = threadIdx.x, lane = tid & 63, w = tid >> 6;
    const int wm = w >> 2, wn = w & 3;
    const int quad = lane >> 4, fr = lane & 15;
    f32x4 acc[4][2] = {};

    const int srow = tid >> 2, sc16 = (tid & 3) * 16;
    for (int k0 = 0; k0 < K; k0 += 64) {
        const unsigned short* ap = A + (size_t)(bm + srow) * K + k0 + sc16;
        *reinterpret_cast<bf16x8*>(&As[srow][sc16])     = *reinterpret_cast<const bf16x8*>(ap);
        *reinterpret_cast<bf16x8*>(&As[srow][sc16 + 8]) = *reinterpret_cast<const bf16x8*>(ap + 8);
        const unsigned short* bp = Bw + (size_t)(bn + srow) * K + k0 + sc16;
        *reinterpret_cast<bf16x8*>(&Bs[srow][sc16])     = *reinterpret_cast<const bf16x8*>(bp);
        *reinterpret_cast<bf16x8*>(&Bs[srow][sc16 + 8]) = *reinterpret_cast<const bf16x8*>(bp + 8);
        __syncthreads();
        #pragma unroll
        for (int ks = 0; ks < 2; ++ks) {
            const int kg = quad * 8 + 32 * ks;
            bf16x8 a[4], bb[2];
            #pragma unroll
            for (int m = 0; m < 4; ++m)
                a[m] = *reinterpret_cast<const bf16x8*>(&As[64 * wm + 16 * m + fr][kg]);
            #pragma unroll
            for (int n = 0; n < 2; ++n)
                bb[n] = *reinterpret_cast<const bf16x8*>(&Bs[32 * wn + 16 * n + fr][kg]);
            #pragma unroll
            for (int m = 0; m < 4; ++m)
                #pragma unroll
                for (int n = 0; n < 2; ++n)
                    acc[m][n] = __builtin_amdgcn_mfma_f32_16x16x32_bf16(a[m], bb[n], acc[m][n], 0, 0, 0);
        }
        __syncthreads();
    }

    #pragma unroll
    for (int n = 0; n < 2; ++n) {
        int col = bn + 32 * wn + 16 * n + fr;
        float bv = bias ? bias[col] : 0.f;
        #pragma unroll
        for (int m = 0; m < 4; ++m)
            #pragma unroll
            for (int i = 0; i < 4; ++i) {
                int row = bm + 64 * wm + 16 * m + quad * 4 + i;
                float v = acc[m][n][i] + bv;
                if (OUT_BF16)
                    ((unsigned short*)Cout)[(size_t)row * N + col] = f2b(v);
                else
                    ((float*)Cout)[(size_t)row * N + col] = v;
                if (STATS) acc[m][n][i] = v;
            }
    }

    if (STATS) {
        const int nchunk = gridDim.y;
        #pragma unroll
        for (int m = 0; m < 4; ++m)
            #pragma unroll
            for (int i = 0; i < 4; ++i) {
                float x = fmaxf(acc[m][0][i], acc[m][1][i]);
                x = fmaxf(x, __shfl_xor(x, 1)); x = fmaxf(x, __shfl_xor(x, 2));
                x = fmaxf(x, __shfl_xor(x, 4)); x = fmaxf(x, __shfl_xor(x, 8));
                if (fr == 0) mred[64 * wm + 16 * m + quad * 4 + i][wn] = x;
            }
        __syncthreads();
        #pragma unroll
        for (int m = 0; m < 4; ++m)
            #pragma unroll
            for (int i = 0; i < 4; ++i) {
                int rl = 64 * wm + 16 * m + quad * 4 + i;
                float Mr = fmaxf(fmaxf(mred[rl][0], mred[rl][1]), fmaxf(mred[rl][2], mred[rl][3]));
                float sv = expf(acc[m][0][i] - Mr) + expf(acc[m][1][i] - Mr);
                sv += __shfl_xor(sv, 1); sv += __shfl_xor(sv, 2);
                sv += __shfl_xor(sv, 4); sv += __shfl_xor(sv, 8);
                if (fr == 0) sred[rl][wn] = sv;
            }
        __syncthreads();
        if (tid < 128) {
            float Mr = fmaxf(fmaxf(mred[tid][0], mred[tid][1]), fmaxf(mred[tid][2], mred[tid][3]));
            float Sv = sred[tid][0] + sred[tid][1] + sred[tid][2] + sred[tid][3];
            stats[(size_t)(bm + tid) * nchunk + blockIdx.y] = make_float2(Mr, Sv);
        }
    }
}

// ---------------- small MFMA GEMM: 64x64 tile, BK=64, 256 thr; grid (N/64, M/64) ----------------
__global__ __launch_bounds__(256) void gemm_small(const unsigned short* __restrict__ A,
                                                  const unsigned short* __restrict__ Bw,
                                                  const float* __restrict__ bias,
                                                  float* __restrict__ Cout, int M, int N, int K) {
    __shared__ unsigned short As[64][72];
    __shared__ unsigned short Bs[64][72];
    const int bm = blockIdx.y * 64, bn = blockIdx.x * 64;
    const int tid = threadIdx.x, lane = tid & 63, w = tid >> 6;
    const int quad = lane >> 4, fr = lane & 15;
    f32x4 acc0[4] = {}, acc1[4] = {}, acc2[4] = {}, acc3[4] = {};
    f32x4* accs[4] = { acc0, acc1, acc2, acc3 };

    const int srow = tid >> 2, sc16 = (tid & 3) * 16;
    for (int k0 = 0; k0 < K; k0 += 64) {
        const unsigned short* ap = A + (size_t)(bm + srow) * K + k0 + sc16;
        *reinterpret_cast<bf16x8*>(&As[srow][sc16])     = *reinterpret_cast<const bf16x8*>(ap);
        *reinterpret_cast<bf16x8*>(&As[srow][sc16 + 8]) = *reinterpret_cast<const bf16x8*>(ap + 8);
        const unsigned short* bp = Bw + (size_t)(bn + srow) * K + k0 + sc16;
        *reinterpret_cast<bf16x8*>(&Bs[srow][sc16])     = *reinterpret_cast<const bf16x8*>(bp);
        *reinterpret_cast<bf16x8*>(&Bs[srow][sc16 + 8]) = *reinterpret_cast<const bf16x8*>(bp + 8);
        __syncthreads();
        #pragma unroll
        for (int ks = 0; ks < 2; ++ks) {
            const int kg = quad * 8 + 32 * ks;
            bf16x8 bb = *reinterpret_cast<const bf16x8*>(&Bs[16 * w + fr][kg]);
            #pragma unroll
            for (int m = 0; m < 4; ++m) {
                bf16x8 a = *reinterpret_cast<const bf16x8*>(&As[16 * m + fr][kg]);
                accs[m][0] = __builtin_amdgcn_mfma_f32_16x16x32_bf16(a, bb, accs[m][0], 0, 0, 0);
            }
        }
        __syncthreads();
    }
    int col = bn + 16 * w + fr;
    float bv = bias ? bias[col] : 0.f;
    #pragma unroll
    for (int m = 0; m < 4; ++m)
        #pragma unroll
        for (int i = 0; i < 4; ++i) {
            int row = bm + 16 * m + quad * 4 + i;
            Cout[(size_t)row * N + col] = accs[m][0][i] + bv;
        }
}

// ---------------- fused per-step kernel: scores + softmax + gi_ctx(KV) + GRU ----------------
// grid (B), 256 thr (4 waves). Block b owns batch b.
__global__ __launch_bounds__(256) void fused_step(const float* __restrict__ ghq,
                                                  const unsigned short* __restrict__ keys,
                                                  const unsigned short* __restrict__ KV,
                                                  const float* __restrict__ va,
                                                  const float* __restrict__ va_b,
                                                  const float* __restrict__ gi_emb,
                                                  float* __restrict__ h,
                                                  unsigned short* __restrict__ hbf,
                                                  unsigned short* __restrict__ outs_bf,
                                                  float* __restrict__ attns,
                                                  float* __restrict__ h_final, int t) {
    const int b = blockIdx.x;
    const int tid = threadIdx.x, lane = tid & 63, wv = tid >> 6;
    __shared__ float ssc[128];   // scores
    __shared__ float sw[128];    // softmax weights

    // per-lane h-chunk [lane*16, lane*16+16)
    float qv[16], vv[16];
    {
        const float* qp = ghq + (size_t)b * 4096 + H3 + lane * 16;
        const float* vp = va + lane * 16;
        #pragma unroll
        for (int j = 0; j < 16; ++j) { qv[j] = qp[j]; vv[j] = vp[j]; }
    }
    // scores: wave wv handles s in [wv*32, wv*32+32)
    const unsigned short* kb = keys + (size_t)b * S * H;
    for (int i = 0; i < 32; ++i) {
        int s = wv * 32 + i;
        const unsigned short* kr = kb + (size_t)s * H + lane * 16;
        ushort8v k0 = *reinterpret_cast<const ushort8v*>(kr);
        ushort8v k1 = *reinterpret_cast<const ushort8v*>(kr + 8);
        float acc = 0.f;
        #pragma unroll
        for (int e = 0; e < 8; ++e) acc += fast_tanh(qv[e] + b2f(k0[e])) * vv[e];
        #pragma unroll
        for (int e = 0; e < 8; ++e) acc += fast_tanh(qv[8 + e] + b2f(k1[e])) * vv[8 + e];
        acc += __shfl_xor(acc, 1);  acc += __shfl_xor(acc, 2);
        acc += __shfl_xor(acc, 4);  acc += __shfl_xor(acc, 8);
        acc += __shfl_xor(acc, 16); acc += __shfl_xor(acc, 32);
        if (lane == 0) ssc[s] = acc + va_b[0];
    }
    __syncthreads();
    // softmax (tid<128; serial LDS-broadcast reduce, redundant per thread)
    if (tid < 128) {
        float mx = -1e30f;
        #pragma unroll 8
        for (int s = 0; s < 128; ++s) mx = fmaxf(mx, ssc[s]);
        float sum = 0.f;
        #pragma unroll 8
        for (int s = 0; s < 128; ++s) sum += __expf(ssc[s] - mx);
        float wvv = __expf(ssc[tid] - mx) / sum;
        sw[tid] = wvv;
        attns[((size_t)b * T + t) * S + tid] = wvv;
    }
    __syncthreads();

    // gi_ctx via KV + GRU. Thread owns j = tid*4 .. +4
    const int j0 = tid * 4;
    float accr[4] = {}, accz[4] = {}, accn[4] = {};
    const unsigned short* kvb = KV + (size_t)b * S * H3;
    #pragma unroll 4
    for (int s = 0; s < S; ++s) {
        float ws = sw[s];
        const unsigned short* row = kvb + (size_t)s * H3;
        uint2 u0 = *reinterpret_cast<const uint2*>(row + j0);
        uint2 u1 = *reinterpret_cast<const uint2*>(row + 1024 + j0);
        uint2 u2 = *reinterpret_cast<const uint2*>(row + 2048 + j0);
        accr[0] += ws * b2f((unsigned short)(u0.x & 0xffff));
        accr[1] += ws * b2f((unsigned short)(u0.x >> 16));
        accr[2] += ws * b2f((unsigned short)(u0.y & 0xffff));
        accr[3] += ws * b2f((unsigned short)(u0.y >> 16));
        accz[0] += ws * b2f((unsigned short)(u1.x & 0xffff));
        accz[1] += ws * b2f((unsigned short)(u1.x >> 16));
        accz[2] += ws * b2f((unsigned short)(u1.y & 0xffff));
        accz[3] += ws * b2f((unsigned short)(u1.y >> 16));
        accn[0] += ws * b2f((unsigned short)(u2.x & 0xffff));
        accn[1] += ws * b2f((unsigned short)(u2.x >> 16));
        accn[2] += ws * b2f((unsigned short)(u2.y & 0xffff));
        accn[3] += ws * b2f((unsigned short)(u2.y >> 16));
    }
    const float* ge = gi_emb + ((size_t)t * B + b) * H3;
    const float* gh = ghq + (size_t)b * 4096;
    float geR[4], geZ[4], geN[4], ghR[4], ghZ[4], ghN[4], hv[4], hn[4];
    *reinterpret_cast<float4*>(geR) = *reinterpret_cast<const float4*>(ge + j0);
    *reinterpret_cast<float4*>(geZ) = *reinterpret_cast<const float4*>(ge + 1024 + j0);
    *reinterpret_cast<float4*>(geN) = *reinterpret_cast<const float4*>(ge + 2048 + j0);
    *reinterpret_cast<float4*>(ghR) = *reinterpret_cast<const float4*>(gh + j0);
    *reinterpret_cast<float4*>(ghZ) = *reinterpret_cast<const float4*>(gh + 1024 + j0);
    *reinterpret_cast<float4*>(ghN) = *reinterpret_cast<const float4*>(gh + 2048 + j0);
    *reinterpret_cast<float4*>(hv)  = *reinterpret_cast<const float4*>(h + (size_t)b * H + j0);
    ushort4 hb, ob;
    unsigned short* hbp = reinterpret_cast<unsigned short*>(&hb);
    unsigned short* obp = reinterpret_cast<unsigned short*>(&ob);
    #pragma unroll
    for (int i = 0; i < 4; ++i) {
        float r = fast_sigmoid(geR[i] + accr[i] + ghR[i]);
        float z = fast_sigmoid(geZ[i] + accz[i] + ghZ[i]);
        float n = fast_tanh(geN[i] + accn[i] + r * ghN[i]);
        hn[i] = (1.f - z) * n + z * hv[i];
        hbp[i] = f2b(hn[i]);
        obp[i] = hbp[i];
    }
    *reinterpret_cast<float4*>(h + (size_t)b * H + j0) = *reinterpret_cast<float4*>(hn);
    *reinterpret_cast<ushort4*>(hbf + (size_t)b * H + j0) = hb;
    *reinterpret_cast<ushort4*>(outs_bf + ((size_t)b * T + t) * H + j0) = ob;
    if (t == T - 1)
        *reinterpret_cast<float4*>(h_final + (size_t)b * H + j0) = *reinterpret_cast<float4*>(hn);
}

// ---------------- log-softmax finalize ----------------
__global__ void lse_kernel(const float2* __restrict__ stats, float* __restrict__ lse) {
    const int row = blockIdx.x;
    const int tid = threadIdx.x;   // 256
    __shared__ float shm[256];
    __shared__ float shs[256];
    float mv = -1e30f, sv = 0.f;
    float2 st = make_float2(-1e30f, 0.f);
    if (tid < NCHUNK) { st = stats[(size_t)row * NCHUNK + tid]; mv = st.x; }
    shm[tid] = mv; __syncthreads();
    for (int off = 128; off > 0; off >>= 1) {
        if (tid < off) shm[tid] = fmaxf(shm[tid], shm[tid + off]);
        __syncthreads();
    }
    float M = shm[0]; __syncthreads();
    if (tid < NCHUNK) sv = st.y * expf(st.x - M);
    shs[tid] = sv; __syncthreads();
    for (int off = 128; off > 0; off >>= 1) {
        if (tid < off) shs[tid] += shs[tid + off];
        __syncthreads();
    }
    if (tid == 0) lse[row] = M + logf(shs[0]);
}

__global__ void sub_lse(float* __restrict__ x, const float* __restrict__ lse) {
    const int n4 = B * T * (V / 4);
    float4* p = reinterpret_cast<float4*>(x);
    for (int i = blockIdx.x * 256 + threadIdx.x; i < n4; i += gridDim.x * 256) {
        int row = i / (V / 4);
        float l = lse[row];
        float4 v = p[i];
        v.x -= l; v.y -= l; v.z -= l; v.w -= l;
        p[i] = v;
    }
}

// ---------------- host ----------------

extern "C" void kernel_launch(void* const* d_in, const int* in_sizes, int n_in,
                              void* d_out, int out_size, void* d_ws, size_t ws_size,
                              hipStream_t stream) {
    const float* enc   = (const float*)d_in[0];
    const float* h0    = (const float*)d_in[1];
    const int*   tgt   = (const int*)d_in[2];
    const float* emb   = (const float*)d_in[3];
    const float* Wa_w  = (const float*)d_in[4];
    const float* Wa_b  = (const float*)d_in[5];
    const float* Ua_w  = (const float*)d_in[6];
    const float* Ua_b  = (const float*)d_in[7];
    const float* Va_w  = (const float*)d_in[8];
    const float* Va_b  = (const float*)d_in[9];
    const float* gwi   = (const float*)d_in[10];
    const float* gwh   = (const float*)d_in[11];
    const float* gbi   = (const float*)d_in[12];
    const float* gbh   = (const float*)d_in[13];
    const float* out_w = (const float*)d_in[14];
    const float* out_b = (const float*)d_in[15];

    float* out       = (float*)d_out;
    float* log_probs = out;                          // [B*T, V]
    float* h_final   = out + (size_t)B * T * V;      // [B, H]
    float* attns     = h_final + (size_t)B * H;      // [B, T, S]

    char* pp = (char*)d_ws;
    auto alloc = [&](size_t bytes) { char* r = pp; pp += (bytes + 255) & ~(size_t)255; return r; };
    unsigned short* ua_bf   = (unsigned short*)alloc((size_t)B * S * H * 2);
    unsigned short* enc_bf  = (unsigned short*)alloc((size_t)B * S * H * 2);
    unsigned short* outw_bf = (unsigned short*)alloc((size_t)V * H * 2);
    unsigned short* KV      = (unsigned short*)alloc((size_t)B * S * H3 * 2);
    unsigned short* Ua_bf   = (unsigned short*)alloc((size_t)H * H * 2);
    unsigned short* Wcat    = (unsigned short*)alloc((size_t)4096 * H * 2);
    unsigned short* Wctx    = (unsigned short*)alloc((size_t)H3 * H * 2);
    unsigned short* Wemb    = (unsigned short*)alloc((size_t)H3 * H * 2);
    float*          catbias = (float*)alloc(4096 * 4);
    unsigned short* embg    = (unsigned short*)alloc((size_t)T * B * H * 2);
    float*          gi_emb  = (float*)alloc((size_t)T * B * H3 * 4);
    float*          hbuf    = (float*)alloc((size_t)B * H * 4);
    unsigned short* hbf     = (unsigned short*)alloc((size_t)B * H * 2);
    float*          ghq     = (float*)alloc((size_t)B * 4096 * 4);
    unsigned short* outs_bf = (unsigned short*)alloc((size_t)B * T * H * 2);
    float2*         stats   = (float2*)alloc((size_t)B * T * NCHUNK * 8);
    float*          lse     = (float*)alloc((size_t)B * T * 4);

    // one-time builds
    conv_f2b<<<B * S * H / 4 / 256, 256, 0, stream>>>(enc, enc_bf, B * S * H / 4);
    conv_f2b<<<V * H / 4 / 256, 256, 0, stream>>>(out_w, outw_bf, V * H / 4);
    conv_f2b<<<H * H / 4 / 256, 256, 0, stream>>>(Ua_w, Ua_bf, H * H / 4);
    conv_f2b<<<B * H / 4 / 256, 256, 0, stream>>>(h0, hbf, B * H / 4);
    build_wcat<<<4096 * H / 4 / 256, 256, 0, stream>>>(gwh, Wa_w, Wcat);
    build_catbias<<<4096 / 256, 256, 0, stream>>>(gbh, Wa_b, catbias);
    build_wslice<<<H3 * H / 4 / 256, 256, 0, stream>>>(gwi, Wemb, 0);
    build_wslice<<<H3 * H / 4 / 256, 256, 0, stream>>>(gwi, Wctx, H);
    embgath_kernel<<<dim3(H / 256, B, T), 256, 0, stream>>>(emb, tgt, embg);
    hipMemcpyAsync(hbuf, h0, (size_t)B * H * sizeof(float), hipMemcpyDeviceToDevice, stream);

    // ua_keys = enc @ Ua_w^T + Ua_b -> bf16 [B*S, H]
    gemm_big<1, 0><<<dim3(B * S / 128, H / 128), 512, 0, stream>>>(
        enc_bf, Ua_bf, Ua_b, ua_bf, nullptr, B * S, H, H);
    // KV = enc @ Wctx^T -> bf16 [B*S, 3072]
    gemm_big<1, 0><<<dim3(B * S / 128, H3 / 128), 512, 0, stream>>>(
        enc_bf, Wctx, nullptr, KV, nullptr, B * S, H3, H);
    // gi_emb = embg @ Wemb^T + gbi -> fp32 [T*B, 3072]
    gemm_big<0, 0><<<dim3(T * B / 128, H3 / 128), 512, 0, stream>>>(
        embg, Wemb, gbi, gi_emb, nullptr, T * B, H3, H);

    for (int t = 0; t < T; ++t) {
        // [gh | q] = h @ [gwh; Wa_w]^T + [gbh; Wa_b]  [64, 4096]
        gemm_small<<<dim3(4096 / 64, 1), 256, 0, stream>>>(hbf, Wcat, catbias, ghq, B, 4096, H);
        fused_step<<<B, 256, 0, stream>>>(ghq, ua_bf, KV, Va_w, Va_b, gi_emb,
                                          hbuf, hbf, outs_bf, attns, h_final, t);
    }

    // logits = outs @ out_w^T + out_b  [640, 32000] + fused softmax stats
    gemm_big<0, 1><<<dim3(B * T / 128, V / 128), 512, 0, stream>>>(
        outs_bf, outw_bf, out_b, log_probs, stats, B * T, V, H);
    lse_kernel<<<B * T, 256, 0, stream>>>(stats, lse);
    sub_lse<<<2048, 256, 0, stream>>>(log_probs, lse);
}

// Round 6
// 985.824 us; speedup vs baseline: 3.9425x; 1.0158x over previous
//
#include <hip/hip_runtime.h>
#include <hip/hip_bf16.h>
#include <cstddef>

#define B 64
#define S 128
#define H 1024
#define V 32000
#define T 10
#define H3 3072
#define NCHUNK 250

typedef __bf16 bf16x8 __attribute__((ext_vector_type(8)));
typedef float f32x4 __attribute__((ext_vector_type(4)));
typedef unsigned short ushort8v __attribute__((ext_vector_type(8)));

__device__ inline unsigned short f2b(float f) {
    __hip_bfloat16 h = __float2bfloat16(f);
    return *reinterpret_cast<unsigned short*>(&h);
}
__device__ inline float b2f(unsigned short u) {
    return __uint_as_float(((unsigned)u) << 16);
}
__device__ inline float fast_tanh(float x) {
    float e = __expf(2.f * x);
    return 1.f - 2.f * __builtin_amdgcn_rcpf(e + 1.f);
}
__device__ inline float fast_sigmoid(float x) {
    return __builtin_amdgcn_rcpf(1.f + __expf(-x));
}

// bijective XCD swizzle (m204): consecutive work ids land on the same XCD
__device__ inline int xcd_swz(int orig, int nwg) {
    int q = nwg >> 3, r = nwg & 7;
    int xcd = orig & 7, idx = orig >> 3;
    int base = (xcd < r) ? xcd * (q + 1) : r * (q + 1) + (xcd - r) * q;
    return base + idx;
}

// ---------------- one-time conversion / build kernels ----------------

__global__ void conv_f2b(const float* __restrict__ src, unsigned short* __restrict__ dst, int n4) {
    int i = blockIdx.x * 256 + threadIdx.x;
    if (i >= n4) return;
    float4 v = reinterpret_cast<const float4*>(src)[i];
    ushort4 o = { f2b(v.x), f2b(v.y), f2b(v.z), f2b(v.w) };
    reinterpret_cast<ushort4*>(dst)[i] = o;
}

__global__ void build_wcat(const float* __restrict__ gwh, const float* __restrict__ Wa_w,
                           unsigned short* __restrict__ dst) {
    int i = blockIdx.x * 256 + threadIdx.x;
    int e = i * 4;
    int n = e >> 10, k = e & 1023;
    const float* src = (n < H3) ? (gwh + (size_t)n * H + k) : (Wa_w + (size_t)(n - H3) * H + k);
    float4 v = *reinterpret_cast<const float4*>(src);
    ushort4 o = { f2b(v.x), f2b(v.y), f2b(v.z), f2b(v.w) };
    reinterpret_cast<ushort4*>(dst)[i] = o;
}

__global__ void build_catbias(const float* __restrict__ gbh, const float* __restrict__ Wa_b,
                              float* __restrict__ dst) {
    int n = blockIdx.x * 256 + threadIdx.x;
    dst[n] = (n < H3) ? gbh[n] : Wa_b[n - H3];
}

__global__ void build_wslice(const float* __restrict__ gwi, unsigned short* __restrict__ dst, int off) {
    int i = blockIdx.x * 256 + threadIdx.x;
    int e = i * 4;
    int n = e >> 10, k = e & 1023;
    float4 v = *reinterpret_cast<const float4*>(gwi + (size_t)n * 2 * H + off + k);
    ushort4 o = { f2b(v.x), f2b(v.y), f2b(v.z), f2b(v.w) };
    reinterpret_cast<ushort4*>(dst)[i] = o;
}

__global__ void embgath_kernel(const float* __restrict__ emb, const int* __restrict__ tgt,
                               unsigned short* __restrict__ dst) {
    int b = blockIdx.y, t = blockIdx.z;
    int j = blockIdx.x * 256 + threadIdx.x;
    int tok = (t == 0) ? 0 : tgt[b * T + (t - 1)];
    dst[((size_t)t * B + b) * H + j] = f2b(emb[(size_t)tok * H + j]);
}

// ---------------- big MFMA GEMM: 128x128 tile, BK=64, 512 thr, 1D grid + XCD swizzle ----------------
// C[M,N] = A[M,K](bf16) @ Bw[N,K]^T(bf16) + bias ; work id decomposes M-fastest
template <int OUT_BF16, int STATS>
__global__ __launch_bounds__(512) void gemm_big(const unsigned short* __restrict__ A,
                                                const unsigned short* __restrict__ Bw,
                                                const float* __restrict__ bias,
                                                void* __restrict__ Cout,
                                                float2* __restrict__ stats,
                                                int M, int N, int K) {
    __shared__ unsigned short As[128][72];
    __shared__ unsigned short Bs[128][72];
    __shared__ float mred[128][4];
    __shared__ float sred[128][4];
    const int wg = xcd_swz(blockIdx.x, gridDim.x);
    const int mtiles = M >> 7;
    const int bm = (wg % mtiles) << 7, bn = (wg / mtiles) << 7;
    const int tid = threadIdx.x, lane = tid & 63, w = tid >> 6;
    const int wm = w >> 2, wn = w & 3;
    const int quad = lane >> 4, fr = lane & 15;
    f32x4 acc[4][2] = {};

    const int srow = tid >> 2, sc16 = (tid & 3) * 16;
    for (int k0 = 0; k0 < K; k0 += 64) {
        const unsigned short* ap = A + (size_t)(bm + srow) * K + k0 + sc16;
        *reinterpret_cast<bf16x8*>(&As[srow][sc16])     = *reinterpret_cast<const bf16x8*>(ap);
        *reinterpret_cast<bf16x8*>(&As[srow][sc16 + 8]) = *reinterpret_cast<const bf16x8*>(ap + 8);
        const unsigned short* bp = Bw + (size_t)(bn + srow) * K + k0 + sc16;
        *reinterpret_cast<bf16x8*>(&Bs[srow][sc16])     = *reinterpret_cast<const bf16x8*>(bp);
        *reinterpret_cast<bf16x8*>(&Bs[srow][sc16 + 8]) = *reinterpret_cast<const bf16x8*>(bp + 8);
        __syncthreads();
        #pragma unroll
        for (int ks = 0; ks < 2; ++ks) {
            const int kg = quad * 8 + 32 * ks;
            bf16x8 a[4], bb[2];
            #pragma unroll
            for (int m = 0; m < 4; ++m)
                a[m] = *reinterpret_cast<const bf16x8*>(&As[64 * wm + 16 * m + fr][kg]);
            #pragma unroll
            for (int n = 0; n < 2; ++n)
                bb[n] = *reinterpret_cast<const bf16x8*>(&Bs[32 * wn + 16 * n + fr][kg]);
            #pragma unroll
            for (int m = 0; m < 4; ++m)
                #pragma unroll
                for (int n = 0; n < 2; ++n)
                    acc[m][n] = __builtin_amdgcn_mfma_f32_16x16x32_bf16(a[m], bb[n], acc[m][n], 0, 0, 0);
        }
        __syncthreads();
    }

    #pragma unroll
    for (int n = 0; n < 2; ++n) {
        int col = bn + 32 * wn + 16 * n + fr;
        float bv = bias ? bias[col] : 0.f;
        #pragma unroll
        for (int m = 0; m < 4; ++m)
            #pragma unroll
            for (int i = 0; i < 4; ++i) {
                int row = bm + 64 * wm + 16 * m + quad * 4 + i;
                float v = acc[m][n][i] + bv;
                if (OUT_BF16)
                    ((unsigned short*)Cout)[(size_t)row * N + col] = f2b(v);
                else
                    ((float*)Cout)[(size_t)row * N + col] = v;
                if (STATS) acc[m][n][i] = v;
            }
    }

    if (STATS) {
        const int nchunk = N >> 7;
        #pragma unroll
        for (int m = 0; m < 4; ++m)
            #pragma unroll
            for (int i = 0; i < 4; ++i) {
                float x = fmaxf(acc[m][0][i], acc[m][1][i]);
                x = fmaxf(x, __shfl_xor(x, 1)); x = fmaxf(x, __shfl_xor(x, 2));
                x = fmaxf(x, __shfl_xor(x, 4)); x = fmaxf(x, __shfl_xor(x, 8));
                if (fr == 0) mred[64 * wm + 16 * m + quad * 4 + i][wn] = x;
            }
        __syncthreads();
        #pragma unroll
        for (int m = 0; m < 4; ++m)
            #pragma unroll
            for (int i = 0; i < 4; ++i) {
                int rl = 64 * wm + 16 * m + quad * 4 + i;
                float Mr = fmaxf(fmaxf(mred[rl][0], mred[rl][1]), fmaxf(mred[rl][2], mred[rl][3]));
                float sv = expf(acc[m][0][i] - Mr) + expf(acc[m][1][i] - Mr);
                sv += __shfl_xor(sv, 1); sv += __shfl_xor(sv, 2);
                sv += __shfl_xor(sv, 4); sv += __shfl_xor(sv, 8);
                if (fr == 0) sred[rl][wn] = sv;
            }
        __syncthreads();
        if (tid < 128) {
            float Mr = fmaxf(fmaxf(mred[tid][0], mred[tid][1]), fmaxf(mred[tid][2], mred[tid][3]));
            float Sv = sred[tid][0] + sred[tid][1] + sred[tid][2] + sred[tid][3];
            stats[(size_t)(bm + tid) * nchunk + (bn >> 7)] = make_float2(Mr, Sv);
        }
    }
}

// ---------------- device-scope barrier for 64 co-resident blocks ----------------
__device__ inline void dev_barrier64(unsigned int* ctr) {
    __syncthreads();
    if (threadIdx.x == 0) {
        __threadfence();                                  // release prior global writes
        atomicAdd(ctr, 1u);
        while (__hip_atomic_load(ctr, __ATOMIC_RELAXED, __HIP_MEMORY_SCOPE_AGENT) < 64u)
            __builtin_amdgcn_s_sleep(1);
        __builtin_amdgcn_fence(__ATOMIC_ACQUIRE, "agent"); // invalidate stale caches
    }
    __syncthreads();
}

// ---------------- per-step kernel: ghq GEMM tile + barrier + attention/GRU ----------------
// grid(64) x 256 thr. Phase A: block n computes ghq[:, n*64:+64]. Phase B: block b = batch b.
__global__ __launch_bounds__(256) void step_kernel(const unsigned short* __restrict__ hbf,
                                                   const unsigned short* __restrict__ Wcat,
                                                   const float* __restrict__ catbias,
                                                   float* __restrict__ ghq,
                                                   const unsigned short* __restrict__ keys,
                                                   const unsigned short* __restrict__ KV,
                                                   const float* __restrict__ va,
                                                   const float* __restrict__ va_b,
                                                   const float* __restrict__ gi_emb,
                                                   float* __restrict__ h,
                                                   unsigned short* __restrict__ hbf_out,
                                                   unsigned short* __restrict__ outs_bf,
                                                   float* __restrict__ attns,
                                                   float* __restrict__ h_final,
                                                   unsigned int* __restrict__ ctr, int t) {
    __shared__ unsigned short As[64][72];
    __shared__ unsigned short Bs[64][72];
    __shared__ float ssc[128];
    __shared__ float sw[128];
    const int tid = threadIdx.x, lane = tid & 63, wv = tid >> 6;
    const int quad = lane >> 4, fr = lane & 15;

    // ===== phase A: ghq[:, bn:bn+64] = hbf @ Wcat[bn:bn+64,:]^T + catbias =====
    {
        const int bn = blockIdx.x << 6;
        f32x4 acc0[4] = {}, acc1[4] = {}, acc2[4] = {}, acc3[4] = {};
        f32x4* accs[4] = { acc0, acc1, acc2, acc3 };
        const int srow = tid >> 2, sc16 = (tid & 3) * 16;
        for (int k0 = 0; k0 < H; k0 += 64) {
            const unsigned short* ap = hbf + (size_t)srow * H + k0 + sc16;
            *reinterpret_cast<bf16x8*>(&As[srow][sc16])     = *reinterpret_cast<const bf16x8*>(ap);
            *reinterpret_cast<bf16x8*>(&As[srow][sc16 + 8]) = *reinterpret_cast<const bf16x8*>(ap + 8);
            const unsigned short* bp = Wcat + (size_t)(bn + srow) * H + k0 + sc16;
            *reinterpret_cast<bf16x8*>(&Bs[srow][sc16])     = *reinterpret_cast<const bf16x8*>(bp);
            *reinterpret_cast<bf16x8*>(&Bs[srow][sc16 + 8]) = *reinterpret_cast<const bf16x8*>(bp + 8);
            __syncthreads();
            #pragma unroll
            for (int ks = 0; ks < 2; ++ks) {
                const int kg = quad * 8 + 32 * ks;
                bf16x8 bb = *reinterpret_cast<const bf16x8*>(&Bs[16 * wv + fr][kg]);
                #pragma unroll
                for (int m = 0; m < 4; ++m) {
                    bf16x8 a = *reinterpret_cast<const bf16x8*>(&As[16 * m + fr][kg]);
                    accs[m][0] = __builtin_amdgcn_mfma_f32_16x16x32_bf16(a, bb, accs[m][0], 0, 0, 0);
                }
            }
            __syncthreads();
        }
        int col = bn + 16 * wv + fr;
        float bv = catbias[col];
        #pragma unroll
        for (int m = 0; m < 4; ++m)
            #pragma unroll
            for (int i = 0; i < 4; ++i) {
                int row = 16 * m + quad * 4 + i;
                ghq[(size_t)row * 4096 + col] = accs[m][0][i] + bv;
            }
    }

    dev_barrier64(ctr);

    // ===== phase B: fused attention + GRU for batch b =====
    const int b = blockIdx.x;
    // per-lane h-chunk [lane*16, +16)
    float qv[16], vv[16];
    {
        const float* qp = ghq + (size_t)b * 4096 + H3 + lane * 16;
        const float* vp = va + lane * 16;
        #pragma unroll
        for (int j = 0; j < 16; ++j) { qv[j] = qp[j]; vv[j] = vp[j]; }
    }
    const unsigned short* kb = keys + (size_t)b * S * H;
    for (int i = 0; i < 32; ++i) {
        int s = wv * 32 + i;
        const unsigned short* kr = kb + (size_t)s * H + lane * 16;
        ushort8v k0 = *reinterpret_cast<const ushort8v*>(kr);
        ushort8v k1 = *reinterpret_cast<const ushort8v*>(kr + 8);
        float acc = 0.f;
        #pragma unroll
        for (int e = 0; e < 8; ++e) acc += fast_tanh(qv[e] + b2f(k0[e])) * vv[e];
        #pragma unroll
        for (int e = 0; e < 8; ++e) acc += fast_tanh(qv[8 + e] + b2f(k1[e])) * vv[8 + e];
        acc += __shfl_xor(acc, 1);  acc += __shfl_xor(acc, 2);
        acc += __shfl_xor(acc, 4);  acc += __shfl_xor(acc, 8);
        acc += __shfl_xor(acc, 16); acc += __shfl_xor(acc, 32);
        if (lane == 0) ssc[s] = acc + va_b[0];
    }
    __syncthreads();
    if (tid < 128) {
        float mx = -1e30f;
        #pragma unroll 8
        for (int s = 0; s < 128; ++s) mx = fmaxf(mx, ssc[s]);
        float sum = 0.f;
        #pragma unroll 8
        for (int s = 0; s < 128; ++s) sum += __expf(ssc[s] - mx);
        float wvv = __expf(ssc[tid] - mx) / sum;
        sw[tid] = wvv;
        attns[((size_t)b * T + t) * S + tid] = wvv;
    }
    __syncthreads();

    const int j0 = tid * 4;
    float accr[4] = {}, accz[4] = {}, accn[4] = {};
    const unsigned short* kvb = KV + (size_t)b * S * H3;
    #pragma unroll 4
    for (int s = 0; s < S; ++s) {
        float ws = sw[s];
        const unsigned short* row = kvb + (size_t)s * H3;
        uint2 u0 = *reinterpret_cast<const uint2*>(row + j0);
        uint2 u1 = *reinterpret_cast<const uint2*>(row + 1024 + j0);
        uint2 u2 = *reinterpret_cast<const uint2*>(row + 2048 + j0);
        accr[0] += ws * b2f((unsigned short)(u0.x & 0xffff));
        accr[1] += ws * b2f((unsigned short)(u0.x >> 16));
        accr[2] += ws * b2f((unsigned short)(u0.y & 0xffff));
        accr[3] += ws * b2f((unsigned short)(u0.y >> 16));
        accz[0] += ws * b2f((unsigned short)(u1.x & 0xffff));
        accz[1] += ws * b2f((unsigned short)(u1.x >> 16));
        accz[2] += ws * b2f((unsigned short)(u1.y & 0xffff));
        accz[3] += ws * b2f((unsigned short)(u1.y >> 16));
        accn[0] += ws * b2f((unsigned short)(u2.x & 0xffff));
        accn[1] += ws * b2f((unsigned short)(u2.x >> 16));
        accn[2] += ws * b2f((unsigned short)(u2.y & 0xffff));
        accn[3] += ws * b2f((unsigned short)(u2.y >> 16));
    }
    const float* ge = gi_emb + ((size_t)t * B + b) * H3;
    const float* gh = ghq + (size_t)b * 4096;
    float geR[4], geZ[4], geN[4], ghR[4], ghZ[4], ghN[4], hv[4], hn[4];
    *reinterpret_cast<float4*>(geR) = *reinterpret_cast<const float4*>(ge + j0);
    *reinterpret_cast<float4*>(geZ) = *reinterpret_cast<const float4*>(ge + 1024 + j0);
    *reinterpret_cast<float4*>(geN) = *reinterpret_cast<const float4*>(ge + 2048 + j0);
    *reinterpret_cast<float4*>(ghR) = *reinterpret_cast<const float4*>(gh + j0);
    *reinterpret_cast<float4*>(ghZ) = *reinterpret_cast<const float4*>(gh + 1024 + j0);
    *reinterpret_cast<float4*>(ghN) = *reinterpret_cast<const float4*>(gh + 2048 + j0);
    *reinterpret_cast<float4*>(hv)  = *reinterpret_cast<const float4*>(h + (size_t)b * H + j0);
    ushort4 hb;
    unsigned short* hbp = reinterpret_cast<unsigned short*>(&hb);
    #pragma unroll
    for (int i = 0; i < 4; ++i) {
        float r = fast_sigmoid(geR[i] + accr[i] + ghR[i]);
        float z = fast_sigmoid(geZ[i] + accz[i] + ghZ[i]);
        float n = fast_tanh(geN[i] + accn[i] + r * ghN[i]);
        hn[i] = (1.f - z) * n + z * hv[i];
        hbp[i] = f2b(hn[i]);
    }
    *reinterpret_cast<float4*>(h + (size_t)b * H + j0) = *reinterpret_cast<float4*>(hn);
    *reinterpret_cast<ushort4*>(hbf_out + (size_t)b * H + j0) = hb;
    *reinterpret_cast<ushort4*>(outs_bf + ((size_t)b * T + t) * H + j0) = hb;
    if (t == T - 1)
        *reinterpret_cast<float4*>(h_final + (size_t)b * H + j0) = *reinterpret_cast<float4*>(hn);
}

// ---------------- log-softmax finalize ----------------
__global__ void lse_kernel(const float2* __restrict__ stats, float* __restrict__ lse) {
    const int row = blockIdx.x;
    const int tid = threadIdx.x;   // 256
    __shared__ float shm[256];
    __shared__ float shs[256];
    float mv = -1e30f, sv = 0.f;
    float2 st = make_float2(-1e30f, 0.f);
    if (tid < NCHUNK) { st = stats[(size_t)row * NCHUNK + tid]; mv = st.x; }
    shm[tid] = mv; __syncthreads();
    for (int off = 128; off > 0; off >>= 1) {
        if (tid < off) shm[tid] = fmaxf(shm[tid], shm[tid + off]);
        __syncthreads();
    }
    float M = shm[0]; __syncthreads();
    if (tid < NCHUNK) sv = st.y * expf(st.x - M);
    shs[tid] = sv; __syncthreads();
    for (int off = 128; off > 0; off >>= 1) {
        if (tid < off) shs[tid] += shs[tid + off];
        __syncthreads();
    }
    if (tid == 0) lse[row] = M + logf(shs[0]);
}

__global__ void sub_lse(float* __restrict__ x, const float* __restrict__ lse) {
    const int n4 = B * T * (V / 4);
    float4* p = reinterpret_cast<float4*>(x);
    for (int i = blockIdx.x * 256 + threadIdx.x; i < n4; i += gridDim.x * 256) {
        int row = i / (V / 4);
        float l = lse[row];
        float4 v = p[i];
        v.x -= l; v.y -= l; v.z -= l; v.w -= l;
        p[i] = v;
    }
}

// ---------------- host ----------------

extern "C" void kernel_launch(void* const* d_in, const int* in_sizes, int n_in,
                              void* d_out, int out_size, void* d_ws, size_t ws_size,
                              hipStream_t stream) {
    const float* enc   = (const float*)d_in[0];
    const float* h0    = (const float*)d_in[1];
    const int*   tgt   = (const int*)d_in[2];
    const float* emb   = (const float*)d_in[3];
    const float* Wa_w  = (const float*)d_in[4];
    const float* Wa_b  = (const float*)d_in[5];
    const float* Ua_w  = (const float*)d_in[6];
    const float* Ua_b  = (const float*)d_in[7];
    const float* Va_w  = (const float*)d_in[8];
    const float* Va_b  = (const float*)d_in[9];
    const float* gwi   = (const float*)d_in[10];
    const float* gwh   = (const float*)d_in[11];
    const float* gbi   = (const float*)d_in[12];
    const float* gbh   = (const float*)d_in[13];
    const float* out_w = (const float*)d_in[14];
    const float* out_b = (const float*)d_in[15];

    float* out       = (float*)d_out;
    float* log_probs = out;                          // [B*T, V]
    float* h_final   = out + (size_t)B * T * V;      // [B, H]
    float* attns     = h_final + (size_t)B * H;      // [B, T, S]

    char* pp = (char*)d_ws;
    auto alloc = [&](size_t bytes) { char* r = pp; pp += (bytes + 255) & ~(size_t)255; return r; };
    unsigned short* ua_bf   = (unsigned short*)alloc((size_t)B * S * H * 2);
    unsigned short* enc_bf  = (unsigned short*)alloc((size_t)B * S * H * 2);
    unsigned short* outw_bf = (unsigned short*)alloc((size_t)V * H * 2);
    unsigned short* KV      = (unsigned short*)alloc((size_t)B * S * H3 * 2);
    unsigned short* Ua_bf   = (unsigned short*)alloc((size_t)H * H * 2);
    unsigned short* Wcat    = (unsigned short*)alloc((size_t)4096 * H * 2);
    unsigned short* Wctx    = (unsigned short*)alloc((size_t)H3 * H * 2);
    unsigned short* Wemb    = (unsigned short*)alloc((size_t)H3 * H * 2);
    float*          catbias = (float*)alloc(4096 * 4);
    unsigned short* embg    = (unsigned short*)alloc((size_t)T * B * H * 2);
    float*          gi_emb  = (float*)alloc((size_t)T * B * H3 * 4);
    float*          hbuf    = (float*)alloc((size_t)B * H * 4);
    unsigned short* hbf     = (unsigned short*)alloc((size_t)B * H * 2);
    float*          ghq     = (float*)alloc((size_t)B * 4096 * 4);
    unsigned short* outs_bf = (unsigned short*)alloc((size_t)B * T * H * 2);
    float2*         stats   = (float2*)alloc((size_t)B * T * NCHUNK * 8);
    float*          lse     = (float*)alloc((size_t)B * T * 4);
    unsigned int*   barriers= (unsigned int*)alloc(T * 4);

    hipMemsetAsync(barriers, 0, T * sizeof(unsigned int), stream);

    // one-time builds
    conv_f2b<<<B * S * H / 4 / 256, 256, 0, stream>>>(enc, enc_bf, B * S * H / 4);
    conv_f2b<<<V * H / 4 / 256, 256, 0, stream>>>(out_w, outw_bf, V * H / 4);
    conv_f2b<<<H * H / 4 / 256, 256, 0, stream>>>(Ua_w, Ua_bf, H * H / 4);
    conv_f2b<<<B * H / 4 / 256, 256, 0, stream>>>(h0, hbf, B * H / 4);
    build_wcat<<<4096 * H / 4 / 256, 256, 0, stream>>>(gwh, Wa_w, Wcat);
    build_catbias<<<4096 / 256, 256, 0, stream>>>(gbh, Wa_b, catbias);
    build_wslice<<<H3 * H / 4 / 256, 256, 0, stream>>>(gwi, Wemb, 0);
    build_wslice<<<H3 * H / 4 / 256, 256, 0, stream>>>(gwi, Wctx, H);
    embgath_kernel<<<dim3(H / 256, B, T), 256, 0, stream>>>(emb, tgt, embg);
    hipMemcpyAsync(hbuf, h0, (size_t)B * H * sizeof(float), hipMemcpyDeviceToDevice, stream);

    // ua_keys = enc @ Ua_w^T + Ua_b -> bf16 [B*S, H]
    gemm_big<1, 0><<<(B * S / 128) * (H / 128), 512, 0, stream>>>(
        enc_bf, Ua_bf, Ua_b, ua_bf, nullptr, B * S, H, H);
    // KV = enc @ Wctx^T -> bf16 [B*S, 3072]
    gemm_big<1, 0><<<(B * S / 128) * (H3 / 128), 512, 0, stream>>>(
        enc_bf, Wctx, nullptr, KV, nullptr, B * S, H3, H);
    // gi_emb = embg @ Wemb^T + gbi -> fp32 [T*B, 3072]
    gemm_big<0, 0><<<(T * B / 128) * (H3 / 128), 512, 0, stream>>>(
        embg, Wemb, gbi, gi_emb, nullptr, T * B, H3, H);

    for (int t = 0; t < T; ++t) {
        step_kernel<<<B, 256, 0, stream>>>(hbf, Wcat, catbias, ghq, ua_bf, KV,
                                           Va_w, Va_b, gi_emb, hbuf, hbf, outs_bf,
                                           attns, h_final, barriers + t, t);
    }

    // logits = outs @ out_w^T + out_b  [640, 32000] + fused softmax stats
    gemm_big<0, 1><<<(B * T / 128) * (V / 128), 512, 0, stream>>>(
        outs_bf, outw_bf, out_b, log_probs, stats, B * T, V, H);
    lse_kernel<<<B * T, 256, 0, stream>>>(stats, lse);
    sub_lse<<<2048, 256, 0, stream>>>(log_probs, lse);
}